// Round 4
// baseline (196.341 us; speedup 1.0000x reference)
//
#include <hip/hip_runtime.h>
#include <math.h>

#define SEQ   2048
#define NH    8
#define DH    64          // p
#define DS    16          // n
#define NBH   512         // BATCH * NH
#define OUTBH 1024        // DH * DS
#define RS    18          // padded LDS row stride (floats) — breaks 16-way conflicts
#define WST   (64 * RS)   // per-wave LDS reduce tile stride (1152 floats)

__device__ __forceinline__ void comp_step(float acc[4][16], const float4& xb,
                                          const float4 bb[4], float w)
{
    float xs[4] = {xb.x * w, xb.y * w, xb.z * w, xb.w * w};
#pragma unroll
    for (int i = 0; i < 4; ++i) {
#pragma unroll
        for (int q = 0; q < 4; ++q) {
            acc[i][4 * q + 0] = fmaf(xs[i], bb[q].x, acc[i][4 * q + 0]);
            acc[i][4 * q + 1] = fmaf(xs[i], bb[q].y, acc[i][4 * q + 1]);
            acc[i][4 * q + 2] = fmaf(xs[i], bb[q].z, acc[i][4 * q + 2]);
            acc[i][4 * q + 3] = fmaf(xs[i], bb[q].w, acc[i][4 * q + 3]);
        }
    }
}

__device__ __forceinline__ void load_step(const float* __restrict__ Xbase,
                                          const float* __restrict__ Bbase,
                                          const float* __restrict__ wseg,
                                          int myt, int NIT, int k,
                                          float4& xb, float4 bb[4], float& wb)
{
    int kk = (k < NIT) ? k : (NIT - 1);          // clamped prefetch (uniform)
    xb = *(const float4*)(Xbase + (size_t)kk * (16 * NH * DH));
    const float* bp = Bbase + (size_t)kk * (16 * NH * DS);
    bb[0] = *(const float4*)(bp + 0);
    bb[1] = *(const float4*)(bp + 4);
    bb[2] = *(const float4*)(bp + 8);
    bb[3] = *(const float4*)(bp + 12);
    wb = wseg[(kk << 4) + myt];
}

// One block per (segment, b, h). 256 threads = 4 waves.
// Wave processes 4 t per iteration: lane (tg=lane>>4, pg=lane&15) loads
// X[t+tg][4p quad pg] (fully coalesced, lane-unique) and its t's B row;
// acc[4][16] per lane over its t-subset; shfl_xor butterfly sums subsets.
__global__ __launch_bounds__(256, 3)
void ssd_state_partial(const float* __restrict__ Xg,
                       const float* __restrict__ Ag,
                       const float* __restrict__ Bg,
                       float* __restrict__ dst,
                       int seglen)
{
    extern __shared__ float sm[];
    float* wseg = sm;               // [seglen]
    float* red  = sm + seglen;      // scan scratch (256 floats), later 4*WST reduce tiles

    const int tid = threadIdx.x;
    const int bid = blockIdx.x;
    const int bh  = bid & (NBH - 1);
    const int g   = bid >> 9;
    const int b   = bh >> 3;
    const int h   = bh & 7;
    const int t0  = g * seglen;

    // ---------------- phase 1: wseg[t] = exp(sum_{s>t} A[b,s,h]) ----------------
    const float* Ab = Ag + (size_t)b * SEQ * NH + h;
    float a[8];
#pragma unroll
    for (int k = 0; k < 8; ++k)
        a[k] = Ab[(size_t)(tid * 8 + k) * NH];
    float tot = 0.f;
#pragma unroll
    for (int k = 0; k < 8; ++k) tot += a[k];
    red[tid] = tot;
    __syncthreads();
    for (int off = 1; off < 256; off <<= 1) {
        float v = red[tid];
        float u = (tid + off < 256) ? red[tid + off] : 0.f;
        __syncthreads();
        red[tid] = v + u;
        __syncthreads();
    }
    float run = (tid < 255) ? red[tid + 1] : 0.f;   // sum over s >= (tid+1)*8
#pragma unroll
    for (int k = 7; k >= 0; --k) {
        int t = tid * 8 + k;
        if (t >= t0 && t < t0 + seglen)
            wseg[t - t0] = expf(run);
        run += a[k];
    }
    __syncthreads();

    // ---------------- phase 2: pipelined weighted outer-product ----------------
    const int wave = tid >> 6;
    const int lane = tid & 63;
    const int tg   = lane >> 4;        // 0..3  : t-offset within the 4-t group
    const int pg   = lane & 15;        // 0..15 : p-quad
    const int myt  = (wave << 2) + tg; // 0..15 : t-offset within 16-t block step

    const float* Xbase = Xg + (((size_t)b * SEQ + t0 + myt) * NH + h) * DH + (pg << 2);
    const float* Bbase = Bg + (((size_t)b * SEQ + t0 + myt) * NH + h) * DS;
    const int NIT = seglen >> 4;       // iterations of 16 t per block (4 per wave)

    float acc[4][16];
#pragma unroll
    for (int i = 0; i < 4; ++i)
#pragma unroll
        for (int j = 0; j < 16; ++j) acc[i][j] = 0.f;

    float4 xbA, xbB, xbC;
    float4 bbA[4], bbB[4], bbC[4];
    float  wA, wB, wC;

    load_step(Xbase, Bbase, wseg, myt, NIT, 0, xbA, bbA, wA);
    load_step(Xbase, Bbase, wseg, myt, NIT, 1, xbB, bbB, wB);
    load_step(Xbase, Bbase, wseg, myt, NIT, 2, xbC, bbC, wC);

    int k = 0;
#pragma unroll 1
    for (; k + 3 <= NIT; k += 3) {
        comp_step(acc, xbA, bbA, wA);
        load_step(Xbase, Bbase, wseg, myt, NIT, k + 3, xbA, bbA, wA);
        comp_step(acc, xbB, bbB, wB);
        load_step(Xbase, Bbase, wseg, myt, NIT, k + 4, xbB, bbB, wB);
        comp_step(acc, xbC, bbC, wC);
        load_step(Xbase, Bbase, wseg, myt, NIT, k + 5, xbC, bbC, wC);
    }
    if (k < NIT)     comp_step(acc, xbA, bbA, wA);
    if (k + 1 < NIT) comp_step(acc, xbB, bbB, wB);

    // ---------------- phase 3: butterfly over t-subsets, LDS cross-wave reduce ----
#pragma unroll
    for (int i = 0; i < 4; ++i)
#pragma unroll
        for (int j = 0; j < 16; ++j) {
            float v = acc[i][j];
            v += __shfl_xor(v, 16, 64);
            v += __shfl_xor(v, 32, 64);
            acc[i][j] = v;
        }

    // lane (pg,tg) stores row r = pg*4+tg → needs acc[tg][*]; select without
    // runtime-indexing the register array (rule #20):
    {
        float* rw = red + wave * WST + (pg * 4 + tg) * RS;
#pragma unroll
        for (int j = 0; j < 16; ++j) {
            float va = (tg & 1) ? acc[1][j] : acc[0][j];
            float vb = (tg & 1) ? acc[3][j] : acc[2][j];
            rw[j] = (tg & 2) ? vb : va;
        }
    }
    __syncthreads();
    {
        int e = tid * 4;
        int r = e >> 4, j = e & 15;
        const float* rp = red + r * RS + j;
        float s0 = rp[0] + rp[WST] + rp[2 * WST] + rp[3 * WST];
        float s1 = rp[1] + rp[1 + WST] + rp[1 + 2 * WST] + rp[1 + 3 * WST];
        float s2 = rp[2] + rp[2 + WST] + rp[2 + 2 * WST] + rp[2 + 3 * WST];
        float s3 = rp[3] + rp[3 + WST] + rp[3 + 2 * WST] + rp[3 + 3 * WST];
        float4 sv; sv.x = s0; sv.y = s1; sv.z = s2; sv.w = s3;
        *(float4*)(dst + (size_t)bid * OUTBH + e) = sv;
    }
}

// Sum the NSEG=4 segment partials into the final output.
__global__ __launch_bounds__(256)
void seg_reduce4(const float* __restrict__ part, float* __restrict__ out)
{
    int i = blockIdx.x * 256 + threadIdx.x;
    size_t o = (size_t)i * 4;
    float4 s = make_float4(0.f, 0.f, 0.f, 0.f);
#pragma unroll
    for (int g2 = 0; g2 < 4; ++g2) {
        float4 v = *(const float4*)(part + (size_t)g2 * NBH * OUTBH + o);
        s.x += v.x; s.y += v.y; s.z += v.z; s.w += v.w;
    }
    *(float4*)(out + o) = s;
}

extern "C" void kernel_launch(void* const* d_in, const int* in_sizes, int n_in,
                              void* d_out, int out_size, void* d_ws, size_t ws_size,
                              hipStream_t stream)
{
    const float* X  = (const float*)d_in[0];
    const float* A  = (const float*)d_in[1];
    const float* Bm = (const float*)d_in[2];
    // d_in[3] (C) is unused by the reference output.
    float* out = (float*)d_out;

    const size_t need = (size_t)4 * NBH * OUTBH * sizeof(float);  // 8 MB
    const int nseg   = (d_ws && ws_size >= need) ? 4 : 1;
    const int seglen = SEQ / nseg;
    float* dst = (nseg == 4) ? (float*)d_ws : out;
    const size_t lds = (size_t)(seglen + 4 * WST) * sizeof(float);

    ssd_state_partial<<<dim3(nseg * NBH), dim3(256), lds, stream>>>(X, A, Bm, dst, seglen);
    if (nseg == 4)
        seg_reduce4<<<dim3((NBH * OUTBH) / 1024), dim3(256), 0, stream>>>((const float*)d_ws, out);
}

// Round 8
// 122.789 us; speedup vs baseline: 1.5990x; 1.5990x over previous
//
#include <hip/hip_runtime.h>
#include <math.h>

#define SEQ   2048
#define NH    8
#define DH    64          // p
#define DS    16          // n
#define NBH   512         // BATCH * NH
#define OUTBH 1024        // DH * DS

// ---- pipelined load/compute helpers (small slots: 4+4+1 = 9 VGPRs each) ----
__device__ __forceinline__ void load_slot(const float* __restrict__ Xp,
                                          const float* __restrict__ Bp,
                                          const float* __restrict__ wseg,
                                          int wave, int NIT, int k,
                                          float4& xv, float4& bv, float& w)
{
    int kk = (k < NIT) ? k : (NIT - 1);     // uniform clamp: harmless re-load
    xv = *(const float4*)(Xp + (size_t)kk * (4 * NH * DH));
    bv = *(const float4*)(Bp + (size_t)kk * (4 * NH * DS));
    w  = wseg[(kk << 2) + wave];
}

__device__ __forceinline__ void comp_slot(float acc[4][4], const float4& xv,
                                          const float4& bv, float w)
{
    float s0 = xv.x * w, s1 = xv.y * w, s2 = xv.z * w, s3 = xv.w * w;
    acc[0][0] = fmaf(s0, bv.x, acc[0][0]);
    acc[0][1] = fmaf(s0, bv.y, acc[0][1]);
    acc[0][2] = fmaf(s0, bv.z, acc[0][2]);
    acc[0][3] = fmaf(s0, bv.w, acc[0][3]);
    acc[1][0] = fmaf(s1, bv.x, acc[1][0]);
    acc[1][1] = fmaf(s1, bv.y, acc[1][1]);
    acc[1][2] = fmaf(s1, bv.z, acc[1][2]);
    acc[1][3] = fmaf(s1, bv.w, acc[1][3]);
    acc[2][0] = fmaf(s2, bv.x, acc[2][0]);
    acc[2][1] = fmaf(s2, bv.y, acc[2][1]);
    acc[2][2] = fmaf(s2, bv.z, acc[2][2]);
    acc[2][3] = fmaf(s2, bv.w, acc[2][3]);
    acc[3][0] = fmaf(s3, bv.x, acc[3][0]);
    acc[3][1] = fmaf(s3, bv.y, acc[3][1]);
    acc[3][2] = fmaf(s3, bv.z, acc[3][2]);
    acc[3][3] = fmaf(s3, bv.w, acc[3][3]);
}

// One block per (segment, b, h). 256 threads = 4 waves; wave handles
// t = t0 + wave + 4k. Lane (pg=lane&15, ng=lane>>4) owns the 4x4 tile at
// (p0=4*pg, n0=4*ng). X load: 16 unique float4 = 256 B/wave; B: 64 B/wave.
// Explicit 4-deep pipeline keeps 8 global loads in flight per wave.
__global__ __launch_bounds__(256, 4)
void ssd_state_partial(const float* __restrict__ Xg,
                       const float* __restrict__ Ag,
                       const float* __restrict__ Bg,
                       float* __restrict__ dst,
                       int seglen)
{
    extern __shared__ float sm[];
    float* wseg = sm;               // [seglen] per-t weights for this segment
    float* red  = sm + seglen;      // 4096 floats: scan buffer, then reduce buffer

    const int tid = threadIdx.x;
    const int bid = blockIdx.x;
    const int bh  = bid & (NBH - 1);
    const int g   = bid >> 9;       // log2(NBH) = 9
    const int b   = bh >> 3;
    const int h   = bh & 7;
    const int t0  = g * seglen;

    // ---------------- phase 1: wseg[t] = exp(sum_{s>t} A[b,s,h]) ----------------
    const float* Ab = Ag + (size_t)b * SEQ * NH + h;
    float a[8];
#pragma unroll
    for (int k = 0; k < 8; ++k)
        a[k] = Ab[(size_t)(tid * 8 + k) * NH];
    float tot = 0.f;
#pragma unroll
    for (int k = 0; k < 8; ++k) tot += a[k];
    red[tid] = tot;
    __syncthreads();
    for (int off = 1; off < 256; off <<= 1) {
        float v = red[tid];
        float u = (tid + off < 256) ? red[tid + off] : 0.f;
        __syncthreads();
        red[tid] = v + u;
        __syncthreads();
    }
    float run = (tid < 255) ? red[tid + 1] : 0.f;   // sum over s >= (tid+1)*8
#pragma unroll
    for (int k = 7; k >= 0; --k) {
        int t = tid * 8 + k;
        if (t >= t0 && t < t0 + seglen)
            wseg[t - t0] = expf(run);
        run += a[k];
    }
    __syncthreads();

    // ---------------- phase 2: 4-deep pipelined weighted outer-product ----------
    const int wave = tid >> 6;
    const int lane = tid & 63;
    const int p0 = (lane & 15) << 2;
    const int n0 = (lane >> 4) << 2;

    const float* Xp = Xg + (((size_t)b * SEQ + t0 + wave) * NH + h) * DH + p0;
    const float* Bp = Bg + (((size_t)b * SEQ + t0 + wave) * NH + h) * DS + n0;
    const int NIT = seglen >> 2;    // t-steps per wave

    float acc[4][4];
#pragma unroll
    for (int i = 0; i < 4; ++i)
#pragma unroll
        for (int j = 0; j < 4; ++j) acc[i][j] = 0.f;

    float4 xvA, xvB, xvC, xvD;
    float4 bvA, bvB, bvC, bvD;
    float  wA, wB, wC, wD;

    load_slot(Xp, Bp, wseg, wave, NIT, 0, xvA, bvA, wA);
    load_slot(Xp, Bp, wseg, wave, NIT, 1, xvB, bvB, wB);
    load_slot(Xp, Bp, wseg, wave, NIT, 2, xvC, bvC, wC);
    load_slot(Xp, Bp, wseg, wave, NIT, 3, xvD, bvD, wD);

    int k = 0;
#pragma unroll 1
    for (; k + 4 <= NIT; k += 4) {
        comp_slot(acc, xvA, bvA, wA);
        load_slot(Xp, Bp, wseg, wave, NIT, k + 4, xvA, bvA, wA);
        comp_slot(acc, xvB, bvB, wB);
        load_slot(Xp, Bp, wseg, wave, NIT, k + 5, xvB, bvB, wB);
        comp_slot(acc, xvC, bvC, wC);
        load_slot(Xp, Bp, wseg, wave, NIT, k + 6, xvC, bvC, wC);
        comp_slot(acc, xvD, bvD, wD);
        load_slot(Xp, Bp, wseg, wave, NIT, k + 7, xvD, bvD, wD);
    }
    if (k < NIT)     comp_slot(acc, xvA, bvA, wA);
    if (k + 1 < NIT) comp_slot(acc, xvB, bvB, wB);
    if (k + 2 < NIT) comp_slot(acc, xvC, bvC, wC);

    // ---------------- phase 3: cross-wave reduce + store (R3-proven form) -------
#pragma unroll
    for (int i = 0; i < 4; ++i) {
        float4 v = make_float4(acc[i][0], acc[i][1], acc[i][2], acc[i][3]);
        *(float4*)&red[wave * OUTBH + (p0 + i) * DS + n0] = v;
    }
    __syncthreads();
    {
        int o = tid * 4;
        float4 r0 = *(const float4*)&red[o];
        float4 r1 = *(const float4*)&red[OUTBH + o];
        float4 r2 = *(const float4*)&red[2 * OUTBH + o];
        float4 r3 = *(const float4*)&red[3 * OUTBH + o];
        float4 s = make_float4(r0.x + r1.x + r2.x + r3.x,
                               r0.y + r1.y + r2.y + r3.y,
                               r0.z + r1.z + r2.z + r3.z,
                               r0.w + r1.w + r2.w + r3.w);
        *(float4*)(dst + (size_t)bid * OUTBH + o) = s;
    }
}

// Sum the NSEG=4 segment partials into the final output.
__global__ __launch_bounds__(256)
void seg_reduce4(const float* __restrict__ part, float* __restrict__ out)
{
    int i = blockIdx.x * 256 + threadIdx.x;
    size_t o = (size_t)i * 4;
    float4 s = make_float4(0.f, 0.f, 0.f, 0.f);
#pragma unroll
    for (int g2 = 0; g2 < 4; ++g2) {
        float4 v = *(const float4*)(part + (size_t)g2 * NBH * OUTBH + o);
        s.x += v.x; s.y += v.y; s.z += v.z; s.w += v.w;
    }
    *(float4*)(out + o) = s;
}

extern "C" void kernel_launch(void* const* d_in, const int* in_sizes, int n_in,
                              void* d_out, int out_size, void* d_ws, size_t ws_size,
                              hipStream_t stream)
{
    const float* X  = (const float*)d_in[0];
    const float* A  = (const float*)d_in[1];
    const float* Bm = (const float*)d_in[2];
    // d_in[3] (C) is unused by the reference output.
    float* out = (float*)d_out;

    const size_t need = (size_t)4 * NBH * OUTBH * sizeof(float);  // 8 MB
    const int nseg   = (d_ws && ws_size >= need) ? 4 : 1;
    const int seglen = SEQ / nseg;
    float* dst = (nseg == 4) ? (float*)d_ws : out;
    const size_t lds = (size_t)(seglen + 4096) * sizeof(float);

    ssd_state_partial<<<dim3(nseg * NBH), dim3(256), lds, stream>>>(X, A, Bm, dst, seglen);
    if (nseg == 4)
        seg_reduce4<<<dim3((NBH * OUTBH) / 1024), dim3(256), 0, stream>>>((const float*)d_ws, out);
}

// Round 9
// 89.854 us; speedup vs baseline: 2.1851x; 1.3665x over previous
//
#include <hip/hip_runtime.h>
#include <math.h>

#define SEQ   2048
#define NH    8
#define DH    64          // p
#define DS    16          // n
#define NBH   512         // BATCH * NH
#define OUTBH 1024        // DH * DS
#define TT    32          // timesteps staged per step
#define XB_FLOATS  (TT * DH)            // 2048 floats = 8 KB
#define BUF_FLOATS (TT * (DH + DS))     // 2560 floats = 10 KB

// Cooperative async stage of TT timesteps of X and B into LDS.
// global_load_lds: LDS dest = wave-uniform base + lane*16 (linear), global src
// per-lane. X: 8 chunks of 4 t (1 KB each), wave w issues chunks {w, w+4}.
// B: 2 chunks of 16 t, waves 0/1.
__device__ __forceinline__ void stage_tile(const float* __restrict__ Xrow,
                                           const float* __restrict__ Brow,
                                           float* Xb, float* Bb,
                                           int tb, int wave, int lane)
{
#pragma unroll
    for (int r = 0; r < 2; ++r) {
        const int t4 = (wave + r * 4) * 4;
        const float* gsrc = Xrow + (size_t)(tb + t4 + (lane >> 4)) * (NH * DH)
                                 + (lane & 15) * 4;
        __builtin_amdgcn_global_load_lds(
            (const __attribute__((address_space(1))) void*)gsrc,
            (__attribute__((address_space(3))) void*)(Xb + t4 * DH), 16, 0, 0);
    }
    if (wave < 2) {
        const int t16 = wave * 16;
        const float* gsrc = Brow + (size_t)(tb + t16 + (lane >> 2)) * (NH * DS)
                                 + (lane & 3) * 4;
        __builtin_amdgcn_global_load_lds(
            (const __attribute__((address_space(1))) void*)gsrc,
            (__attribute__((address_space(3))) void*)(Bb + t16 * DS), 16, 0, 0);
    }
}

// One block per (segment, b, h). 256 threads = 4 waves. Double-buffered LDS
// staging (2-phase schedule): STAGE(next) -> compute(cur) -> barrier -> swap.
// Lane (pg=lane&15, ng=lane>>4) owns the 4x4 tile at (4*pg, 4*ng); wave w
// computes t in [w*8, w*8+8) of each 32-t tile; cross-wave reduce at the end.
__global__ __launch_bounds__(256, 4)
void ssd_state_stage(const float* __restrict__ Xg,
                     const float* __restrict__ Ag,
                     const float* __restrict__ Bg,
                     float* __restrict__ dst,
                     int seglen)
{
    extern __shared__ float sm[];
    float* wseg    = sm;               // [seglen] weights
    float* stage   = sm + seglen;      // [2][BUF_FLOATS] staging (dbuf)
    float* scratch = stage;            // aliased: phase-1 scan + epilogue reduce

    const int tid = threadIdx.x;
    const int bid = blockIdx.x;
    const int bh  = bid & (NBH - 1);
    const int g   = bid >> 9;          // log2(NBH) = 9
    const int b   = bh >> 3;
    const int h   = bh & 7;
    const int t0  = g * seglen;

    // ---------------- phase 1: wseg[t] = exp(sum_{s>t} A[b,s,h]) ----------------
    const float* Ab = Ag + (size_t)b * SEQ * NH + h;
    float a[8];
#pragma unroll
    for (int k = 0; k < 8; ++k)
        a[k] = Ab[(size_t)(tid * 8 + k) * NH];
    float tot = 0.f;
#pragma unroll
    for (int k = 0; k < 8; ++k) tot += a[k];
    scratch[tid] = tot;
    __syncthreads();
    for (int off = 1; off < 256; off <<= 1) {
        float v = scratch[tid];
        float u = (tid + off < 256) ? scratch[tid + off] : 0.f;
        __syncthreads();
        scratch[tid] = v + u;
        __syncthreads();
    }
    float run = (tid < 255) ? scratch[tid + 1] : 0.f;   // sum over s >= (tid+1)*8
#pragma unroll
    for (int k = 7; k >= 0; --k) {
        int t = tid * 8 + k;
        if (t >= t0 && t < t0 + seglen)
            wseg[t - t0] = expf(run);
        run += a[k];
    }
    __syncthreads();

    // ---------------- phase 2: 2-phase staged weighted outer-product ------------
    const int wave = tid >> 6;
    const int lane = tid & 63;
    const int pg = lane & 15;
    const int ng = lane >> 4;

    const float* Xrow = Xg + (((size_t)b * SEQ + t0) * NH + h) * DH;
    const float* Brow = Bg + (((size_t)b * SEQ + t0) * NH + h) * DS;
    const int NSTEP = seglen / TT;

    float acc[4][4];
#pragma unroll
    for (int i = 0; i < 4; ++i)
#pragma unroll
        for (int j = 0; j < 4; ++j) acc[i][j] = 0.f;

    int cur = 0;
    stage_tile(Xrow, Brow, stage, stage + XB_FLOATS, 0, wave, lane);
    __syncthreads();   // drains vmcnt(0): tile 0 landed

#pragma unroll 1
    for (int s = 0; s < NSTEP; ++s) {
        if (s + 1 < NSTEP) {
            float* nb = stage + (cur ^ 1) * BUF_FLOATS;
            stage_tile(Xrow, Brow, nb, nb + XB_FLOATS, (s + 1) * TT, wave, lane);
        }
        const float* Xb = stage + cur * BUF_FLOATS;
        const float* xr = Xb + (wave * 8) * DH + pg * 4;
        const float* br = Xb + XB_FLOATS + (wave * 8) * DS + ng * 4;
        const float* wp = wseg + s * TT + wave * 8;
#pragma unroll
        for (int j = 0; j < 8; ++j) {
            float4 xv = *(const float4*)(xr + j * DH);
            float4 bv = *(const float4*)(br + j * DS);
            float wt  = wp[j];
            float s0 = xv.x * wt, s1 = xv.y * wt, s2 = xv.z * wt, s3 = xv.w * wt;
            acc[0][0] = fmaf(s0, bv.x, acc[0][0]);
            acc[0][1] = fmaf(s0, bv.y, acc[0][1]);
            acc[0][2] = fmaf(s0, bv.z, acc[0][2]);
            acc[0][3] = fmaf(s0, bv.w, acc[0][3]);
            acc[1][0] = fmaf(s1, bv.x, acc[1][0]);
            acc[1][1] = fmaf(s1, bv.y, acc[1][1]);
            acc[1][2] = fmaf(s1, bv.z, acc[1][2]);
            acc[1][3] = fmaf(s1, bv.w, acc[1][3]);
            acc[2][0] = fmaf(s2, bv.x, acc[2][0]);
            acc[2][1] = fmaf(s2, bv.y, acc[2][1]);
            acc[2][2] = fmaf(s2, bv.z, acc[2][2]);
            acc[2][3] = fmaf(s2, bv.w, acc[2][3]);
            acc[3][0] = fmaf(s3, bv.x, acc[3][0]);
            acc[3][1] = fmaf(s3, bv.y, acc[3][1]);
            acc[3][2] = fmaf(s3, bv.z, acc[3][2]);
            acc[3][3] = fmaf(s3, bv.w, acc[3][3]);
        }
        __syncthreads();   // vmcnt(0): next tile landed; all reads of cur done
        cur ^= 1;
    }

    // ---------------- phase 3: cross-wave reduce + store (R3-proven form) -------
    float* red = scratch;   // staging area is dead past the last barrier
#pragma unroll
    for (int i = 0; i < 4; ++i) {
        float4 v = make_float4(acc[i][0], acc[i][1], acc[i][2], acc[i][3]);
        *(float4*)&red[wave * OUTBH + (pg * 4 + i) * DS + ng * 4] = v;
    }
    __syncthreads();
    {
        int o = tid * 4;
        float4 r0 = *(const float4*)&red[o];
        float4 r1 = *(const float4*)&red[OUTBH + o];
        float4 r2 = *(const float4*)&red[2 * OUTBH + o];
        float4 r3 = *(const float4*)&red[3 * OUTBH + o];
        float4 sv = make_float4(r0.x + r1.x + r2.x + r3.x,
                                r0.y + r1.y + r2.y + r3.y,
                                r0.z + r1.z + r2.z + r3.z,
                                r0.w + r1.w + r2.w + r3.w);
        *(float4*)(dst + (size_t)bid * OUTBH + o) = sv;
    }
}

// Sum the NSEG=4 segment partials into the final output.
__global__ __launch_bounds__(256)
void seg_reduce4(const float* __restrict__ part, float* __restrict__ out)
{
    int i = blockIdx.x * 256 + threadIdx.x;
    size_t o = (size_t)i * 4;
    float4 s = make_float4(0.f, 0.f, 0.f, 0.f);
#pragma unroll
    for (int g2 = 0; g2 < 4; ++g2) {
        float4 v = *(const float4*)(part + (size_t)g2 * NBH * OUTBH + o);
        s.x += v.x; s.y += v.y; s.z += v.z; s.w += v.w;
    }
    *(float4*)(out + o) = s;
}

extern "C" void kernel_launch(void* const* d_in, const int* in_sizes, int n_in,
                              void* d_out, int out_size, void* d_ws, size_t ws_size,
                              hipStream_t stream)
{
    const float* X  = (const float*)d_in[0];
    const float* A  = (const float*)d_in[1];
    const float* Bm = (const float*)d_in[2];
    // d_in[3] (C) is unused by the reference output.
    float* out = (float*)d_out;

    const size_t need = (size_t)4 * NBH * OUTBH * sizeof(float);  // 8 MB
    const int nseg   = (d_ws && ws_size >= need) ? 4 : 1;
    const int seglen = SEQ / nseg;
    float* dst = (nseg == 4) ? (float*)d_ws : out;
    const size_t lds = (size_t)(seglen + 2 * BUF_FLOATS) * sizeof(float);

    ssd_state_stage<<<dim3(nseg * NBH), dim3(256), lds, stream>>>(X, A, Bm, dst, seglen);
    if (nseg == 4)
        seg_reduce4<<<dim3((NBH * OUTBH) / 1024), dim3(256), 0, stream>>>((const float*)d_ws, out);
}

// Round 10
// 88.449 us; speedup vs baseline: 2.2198x; 1.0159x over previous
//
#include <hip/hip_runtime.h>
#include <math.h>

#define SEQ   2048
#define NH    8
#define DH    64          // p
#define DS    16          // n
#define NBH   512         // BATCH * NH
#define OUTBH 1024        // DH * DS
#define TT    32          // timesteps staged per tile
#define XB_FLOATS  (TT * DH)            // 2048 floats = 8 KB
#define BUF_FLOATS (TT * (DH + DS))     // 2560 floats = 10 KB
#define NBUF  3

// Cooperative async stage of TT timesteps of X and B into LDS.
// X: 8 chunks of 4 t (1 KB each), wave w issues chunks {w, w+4} (2 ops).
// B: 2 chunks of 16 t (1 KB each), waves 0/1 (1 op).
// Per-tile vmem ops per wave: waves 0,1 -> 3; waves 2,3 -> 2.
__device__ __forceinline__ void stage_tile(const float* __restrict__ Xrow,
                                           const float* __restrict__ Brow,
                                           float* Xb, float* Bb,
                                           int tb, int wave, int lane)
{
#pragma unroll
    for (int r = 0; r < 2; ++r) {
        const int t4 = (wave + r * 4) * 4;
        const float* gsrc = Xrow + (size_t)(tb + t4 + (lane >> 4)) * (NH * DH)
                                 + (lane & 15) * 4;
        __builtin_amdgcn_global_load_lds(
            (const __attribute__((address_space(1))) void*)gsrc,
            (__attribute__((address_space(3))) void*)(Xb + t4 * DH), 16, 0, 0);
    }
    if (wave < 2) {
        const int t16 = wave * 16;
        const float* gsrc = Brow + (size_t)(tb + t16 + (lane >> 2)) * (NH * DS)
                                 + (lane & 3) * 4;
        __builtin_amdgcn_global_load_lds(
            (const __attribute__((address_space(1))) void*)gsrc,
            (__attribute__((address_space(3))) void*)(Bb + t16 * DS), 16, 0, 0);
    }
}

// One block per (segment, b, h). 256 threads = 4 waves. 3-buffer LDS pipeline
// with counted vmcnt (loads stay in flight across barriers; no vmcnt(0) drain
// in the main loop). Lane (pg=lane&15, ng=lane>>4) owns the 4x4 tile at
// (4*pg, 4*ng); wave w computes t in [w*8, w*8+8) of each 32-t tile.
__global__ __launch_bounds__(256, 4)
void ssd_state_pipe(const float* __restrict__ Xg,
                    const float* __restrict__ Ag,
                    const float* __restrict__ Bg,
                    float* __restrict__ dst,
                    int seglen)
{
    extern __shared__ float sm[];
    float* wseg    = sm;               // [seglen] weights
    float* stage   = sm + seglen;      // [NBUF][BUF_FLOATS] staging
    float* scratch = stage;            // aliased: phase-1 scan + epilogue reduce

    const int tid = threadIdx.x;
    const int bid = blockIdx.x;
    const int bh  = bid & (NBH - 1);
    const int g   = bid >> 9;          // log2(NBH) = 9
    const int b   = bh >> 3;
    const int h   = bh & 7;
    const int t0  = g * seglen;

    // ---------------- phase 1: wseg[t] = exp(sum_{s>t} A[b,s,h]) ----------------
    const float* Ab = Ag + (size_t)b * SEQ * NH + h;
    float a[8];
#pragma unroll
    for (int k = 0; k < 8; ++k)
        a[k] = Ab[(size_t)(tid * 8 + k) * NH];
    float tot = 0.f;
#pragma unroll
    for (int k = 0; k < 8; ++k) tot += a[k];
    scratch[tid] = tot;
    __syncthreads();
    for (int off = 1; off < 256; off <<= 1) {
        float v = scratch[tid];
        float u = (tid + off < 256) ? scratch[tid + off] : 0.f;
        __syncthreads();
        scratch[tid] = v + u;
        __syncthreads();
    }
    float run = (tid < 255) ? scratch[tid + 1] : 0.f;   // sum over s >= (tid+1)*8
#pragma unroll
    for (int k = 7; k >= 0; --k) {
        int t = tid * 8 + k;
        if (t >= t0 && t < t0 + seglen)
            wseg[t - t0] = expf(run);
        run += a[k];
    }
    __syncthreads();   // wseg ready; also all scratch reads done before staging

    // ---------------- phase 2: counted-vmcnt 3-buffer pipeline ------------------
    const int wave = tid >> 6;
    const int lane = tid & 63;
    const int pg = lane & 15;
    const int ng = lane >> 4;

    const float* Xrow = Xg + (((size_t)b * SEQ + t0) * NH + h) * DH;
    const float* Brow = Bg + (((size_t)b * SEQ + t0) * NH + h) * DS;
    const int NSTEP = seglen / TT;

    float acc[4][4];
#pragma unroll
    for (int i = 0; i < 4; ++i)
#pragma unroll
        for (int j = 0; j < 4; ++j) acc[i][j] = 0.f;

    // prologue: tiles 0 and 1 in flight (issue order matters for vmcnt FIFO)
    stage_tile(Xrow, Brow, stage, stage + XB_FLOATS, 0, wave, lane);
    asm volatile("" ::: "memory");
    {
        float* nb = stage + BUF_FLOATS;
        stage_tile(Xrow, Brow, nb, nb + XB_FLOATS,
                   (1 < NSTEP ? 1 : NSTEP - 1) * TT, wave, lane);
    }
    asm volatile("" ::: "memory");

    int cbuf = 0;    // buffer holding tile s
    int ibuf = 2;    // buffer to stage tile s+2 into
#pragma unroll 1
    for (int s = 0; s < NSTEP; ++s) {
        // wait: own tile-s ops landed (tile s+1 stays in flight); prior LDS
        // reads drained (buffer ibuf is safe to overwrite after the barrier)
        if (wave < 2)
            asm volatile("s_waitcnt vmcnt(3) lgkmcnt(0)" ::: "memory");
        else
            asm volatile("s_waitcnt vmcnt(2) lgkmcnt(0)" ::: "memory");
        __builtin_amdgcn_s_barrier();   // all waves' tile-s stages landed
        asm volatile("" ::: "memory");

        // issue tile s+2 (clamped re-stage at the tail keeps op counts uniform;
        // its target buffer is never read again)
        {
            int nxt = (s + 2 < NSTEP) ? s + 2 : NSTEP - 1;
            float* nb = stage + ibuf * BUF_FLOATS;
            stage_tile(Xrow, Brow, nb, nb + XB_FLOATS, nxt * TT, wave, lane);
        }
        asm volatile("" ::: "memory");

        // compute tile s from cbuf
        const float* Xb = stage + cbuf * BUF_FLOATS;
        const float* xr = Xb + (wave * 8) * DH + pg * 4;
        const float* br = Xb + XB_FLOATS + (wave * 8) * DS + ng * 4;
        const float* wp = wseg + s * TT + wave * 8;
#pragma unroll
        for (int j = 0; j < 8; ++j) {
            float4 xv = *(const float4*)(xr + j * DH);
            float4 bv = *(const float4*)(br + j * DS);
            float wt  = wp[j];
            float s0 = xv.x * wt, s1 = xv.y * wt, s2 = xv.z * wt, s3 = xv.w * wt;
            acc[0][0] = fmaf(s0, bv.x, acc[0][0]);
            acc[0][1] = fmaf(s0, bv.y, acc[0][1]);
            acc[0][2] = fmaf(s0, bv.z, acc[0][2]);
            acc[0][3] = fmaf(s0, bv.w, acc[0][3]);
            acc[1][0] = fmaf(s1, bv.x, acc[1][0]);
            acc[1][1] = fmaf(s1, bv.y, acc[1][1]);
            acc[1][2] = fmaf(s1, bv.z, acc[1][2]);
            acc[1][3] = fmaf(s1, bv.w, acc[1][3]);
            acc[2][0] = fmaf(s2, bv.x, acc[2][0]);
            acc[2][1] = fmaf(s2, bv.y, acc[2][1]);
            acc[2][2] = fmaf(s2, bv.z, acc[2][2]);
            acc[2][3] = fmaf(s2, bv.w, acc[2][3]);
            acc[3][0] = fmaf(s3, bv.x, acc[3][0]);
            acc[3][1] = fmaf(s3, bv.y, acc[3][1]);
            acc[3][2] = fmaf(s3, bv.z, acc[3][2]);
            acc[3][3] = fmaf(s3, bv.w, acc[3][3]);
        }

        cbuf = (cbuf == NBUF - 1) ? 0 : cbuf + 1;
        ibuf = (ibuf == NBUF - 1) ? 0 : ibuf + 1;
    }

    // drain the clamped tail stages before re-using staging LDS as reduce buffer
    asm volatile("s_waitcnt vmcnt(0)" ::: "memory");
    __syncthreads();

    // ---------------- phase 3: cross-wave reduce + store -------------------------
    float* red = scratch;
#pragma unroll
    for (int i = 0; i < 4; ++i) {
        float4 v = make_float4(acc[i][0], acc[i][1], acc[i][2], acc[i][3]);
        *(float4*)&red[wave * OUTBH + (pg * 4 + i) * DS + ng * 4] = v;
    }
    __syncthreads();
    {
        int o = tid * 4;
        float4 r0 = *(const float4*)&red[o];
        float4 r1 = *(const float4*)&red[OUTBH + o];
        float4 r2 = *(const float4*)&red[2 * OUTBH + o];
        float4 r3 = *(const float4*)&red[3 * OUTBH + o];
        float4 sv = make_float4(r0.x + r1.x + r2.x + r3.x,
                                r0.y + r1.y + r2.y + r3.y,
                                r0.z + r1.z + r2.z + r3.z,
                                r0.w + r1.w + r2.w + r3.w);
        *(float4*)(dst + (size_t)bid * OUTBH + o) = sv;
    }
}

// Sum the NSEG=4 segment partials into the final output.
__global__ __launch_bounds__(256)
void seg_reduce4(const float* __restrict__ part, float* __restrict__ out)
{
    int i = blockIdx.x * 256 + threadIdx.x;
    size_t o = (size_t)i * 4;
    float4 s = make_float4(0.f, 0.f, 0.f, 0.f);
#pragma unroll
    for (int g2 = 0; g2 < 4; ++g2) {
        float4 v = *(const float4*)(part + (size_t)g2 * NBH * OUTBH + o);
        s.x += v.x; s.y += v.y; s.z += v.z; s.w += v.w;
    }
    *(float4*)(out + o) = s;
}

extern "C" void kernel_launch(void* const* d_in, const int* in_sizes, int n_in,
                              void* d_out, int out_size, void* d_ws, size_t ws_size,
                              hipStream_t stream)
{
    const float* X  = (const float*)d_in[0];
    const float* A  = (const float*)d_in[1];
    const float* Bm = (const float*)d_in[2];
    // d_in[3] (C) is unused by the reference output.
    float* out = (float*)d_out;

    const size_t need = (size_t)4 * NBH * OUTBH * sizeof(float);  // 8 MB
    const int nseg   = (d_ws && ws_size >= need) ? 4 : 1;
    const int seglen = SEQ / nseg;
    float* dst = (nseg == 4) ? (float*)d_ws : out;
    const size_t lds = (size_t)(seglen + NBUF * BUF_FLOATS) * sizeof(float);

    ssd_state_pipe<<<dim3(nseg * NBH), dim3(256), lds, stream>>>(X, A, Bm, dst, seglen);
    if (nseg == 4)
        seg_reduce4<<<dim3((NBH * OUTBH) / 1024), dim3(256), 0, stream>>>((const float*)d_ws, out);
}